// Round 15
// baseline (151.086 us; speedup 1.0000x reference)
//
#include <hip/hip_runtime.h>
#include <hip/hip_bf16.h>

// Joiner: logits[n,t,u,v] = sum_d tanh(enc[n,t,d]+dec[n,u,d]) * W[v,d] + b[v]
// N=8 T=200 U=100 D=512 V=500  -> GEMM M=160000, K=512, N=500 (padded 512)
//
// R12 = R9's V-split shape (BN=256 via blockIdx.y, 256thr, acc[4][4]=64)
//     + R10's RAW (lgkm-only) barriers so the reg-dbuf B prefetch survives
//       the barrier (T4; R9 failed only because __syncthreads drained vmcnt)
//     + __launch_bounds__(256,3): ~150 total regs -> 3 blocks/CU, 12
//       waves/CU (R10 pinned at 2 waves/SIMD by acc=128).
// Accepted costs: 2x tanh redundancy (~8us chip trans), 2x B-L2 (37us, under
// the 51us write floor). Streamed LDS epilogue w/ raw barriers.

#define NB 8
#define TT 200
#define UU 100
#define DD 512
#define VV 500
#define VP 512
#define BM 64
#define BNB 256            // per-block V-columns
#define BK 32
#define KSTEPS 16          // 512/32
#define THREADS 256
#define LDA 40             // BK + 8 pad (ushort units, 80B row stride)
#define LCH 264            // epilogue chunk row stride in f32
#define MROWS (NB*TT*UU)   // 160000
#define MBLOCKS (MROWS/BM) // 2500

typedef __attribute__((ext_vector_type(4))) float         f32x4;
typedef __attribute__((ext_vector_type(8))) short         s16x8;
typedef __attribute__((ext_vector_type(4))) unsigned int  u32x4;

#define RAW_BAR() do { asm volatile("s_waitcnt lgkmcnt(0)" ::: "memory"); \
                       __builtin_amdgcn_s_barrier(); } while (0)

__device__ __forceinline__ unsigned short f2bf(float f) {
    unsigned int u = __builtin_bit_cast(unsigned int, f);
    u = (u + 0x7FFFu + ((u >> 16) & 1u)) >> 16;   // round-to-nearest-even
    return (unsigned short)u;
}

// pack 2 f32 -> 2 bf16 (RNE) in one instruction
__device__ __forceinline__ unsigned int cvt_pk_bf16(float a, float b) {
    unsigned int r;
    asm("v_cvt_pk_bf16_f32 %0, %1, %2" : "=v"(r) : "v"(a), "v"(b));
    return r;
}

__device__ __forceinline__ float fast_tanh(float x) {
    // tanh(x) = 1 - 2/(1+2^(2x*log2e)); saturations via exp inf/0
    float e = __builtin_amdgcn_exp2f(x * 2.88539008177793f);
    return __builtin_fmaf(-2.0f, __builtin_amdgcn_rcpf(e + 1.0f), 1.0f);
}

// ---- prep: W (500x512 f32) -> bf16, padded to 512 rows, tiled [kc][v][32] ----
__global__ void prep_w(const float* __restrict__ W, unsigned short* __restrict__ Wt) {
    int idx = blockIdx.x * 256 + threadIdx.x;   // 0 .. 512*512-1
    int k = idx & 511;
    int v = idx >> 9;
    float val = (v < VV) ? W[v * DD + k] : 0.0f;
    Wt[(k >> 5) * (VP * BK) + v * BK + (k & 31)] = f2bf(val);
}

// One K-step. At entry: CUR holds A[kc] (barrier passed), BC holds B[kc]
// (loads in flight, counted-vmcnt at consume), e/d regs hold enc/dec[kc+1].
#define KBODY(kc, CUR, NXT, BC, BNX)                                          \
  {                                                                           \
    /* issue next step's B fragments (stay in flight across the barrier) */   \
    if ((kc) < KSTEPS - 1) {                                                  \
      _Pragma("unroll")                                                       \
      for (int f = 0; f < 4; ++f)                                             \
        BNX[f] = *(const s16x8*)(wptr + ((kc)+1) * (VP * BK) + f * (16*BK));  \
    }                                                                         \
    /* A fragments for this step */                                           \
    s16x8 aF[4];                                                              \
    _Pragma("unroll")                                                         \
    for (int m = 0; m < 4; ++m)                                               \
      aF[m] = *(const s16x8*)(&CUR[(m * 16 + lr) * LDA + lk * 8]);            \
    /* stage A[kc+1] from e/d regs, then load e/d for kc+2 */                 \
    if ((kc) < KSTEPS - 1) {                                                  \
      u32x4 wds;                                                              \
      wds[0] = cvt_pk_bf16(fast_tanh(e0[0]+d0[0]), fast_tanh(e0[1]+d0[1]));   \
      wds[1] = cvt_pk_bf16(fast_tanh(e0[2]+d0[2]), fast_tanh(e0[3]+d0[3]));   \
      wds[2] = cvt_pk_bf16(fast_tanh(e1[0]+d1[0]), fast_tanh(e1[1]+d1[1]));   \
      wds[3] = cvt_pk_bf16(fast_tanh(e1[2]+d1[2]), fast_tanh(e1[3]+d1[3]));   \
      *(u32x4*)(&NXT[srow * LDA + sk]) = wds;                                 \
      if ((kc) < KSTEPS - 2) {                                                \
        const float* e2 = ep + ((kc)+2) * BK;                                 \
        const float* d2 = dp + ((kc)+2) * BK;                                 \
        e0 = *(const f32x4*)(e2);  e1 = *(const f32x4*)(e2 + 4);              \
        d0 = *(const f32x4*)(d2);  d1 = *(const f32x4*)(d2 + 4);              \
      }                                                                       \
    }                                                                         \
    /* 16 MFMAs on BC (counted vmcnt at consume, not 0) */                    \
    __builtin_amdgcn_s_setprio(1);                                            \
    _Pragma("unroll")                                                         \
    for (int m = 0; m < 4; ++m)                                               \
      _Pragma("unroll")                                                       \
      for (int f = 0; f < 4; ++f)                                             \
        acc[m][f] = __builtin_amdgcn_mfma_f32_16x16x32_bf16(aF[m], BC[f],     \
                                                            acc[m][f],0,0,0); \
    __builtin_amdgcn_s_setprio(0);                                            \
    /* raw barrier: drain LDS only, keep global loads in flight */            \
    if ((kc) < KSTEPS - 1) RAW_BAR();                                         \
  }

__global__ __launch_bounds__(THREADS, 3) void joiner_kernel(
    const float* __restrict__ enc, const float* __restrict__ dec,
    const unsigned short* __restrict__ Wt, const float* __restrict__ bias,
    float* __restrict__ out)
{
    // union: K-loop A dbuf (2x5120 B) / epilogue chunk 16 x LCH f32 (16896 B)
    __shared__ __align__(16) char smem[16 * LCH * 4];
    unsigned short* lA0 = (unsigned short*)smem;
    unsigned short* lA1 = (unsigned short*)(smem + BM * LDA * 2);

    const int tid  = threadIdx.x;
    const int mb   = blockIdx.x;
    const int vb   = blockIdx.y;     // 0,1: which 256-col slab of V
    const int lane = tid & 63;
    const int wn   = tid >> 6;       // 0..3: 64-col quarter of the slab
    const int lr   = lane & 15;
    const int lk   = lane >> 4;

    // staging: each thread produces 8 activations of one row
    const int srow = tid >> 2;          // 0..63
    const int sk   = (tid & 3) << 3;    // 0,8,16,24

    int r   = mb * BM + srow;
    int n   = r / (TT * UU);
    int rem = r - n * (TT * UU);
    int t   = rem / UU;
    int u   = rem - t * UU;
    const float* ep = enc + (n * TT + t) * DD + sk;
    const float* dp = dec + (n * UU + u) * DD + sk;

    // per-thread B pointer: v = vb*256 + wn*64 + f*16 + lr, k = lk*8
    const unsigned short* wptr = Wt + (vb * BNB + wn * 64 + lr) * BK + lk * 8;

    f32x4 e0, e1, d0, d1;
    s16x8 b0[4], b1[4];

    // ---- prologue: e/d[0], issue B[0], stage A[0], e/d[1], raw barrier ----
    e0 = *(const f32x4*)(ep);     e1 = *(const f32x4*)(ep + 4);
    d0 = *(const f32x4*)(dp);     d1 = *(const f32x4*)(dp + 4);
    #pragma unroll
    for (int f = 0; f < 4; ++f)
        b0[f] = *(const s16x8*)(wptr + f * (16 * BK));
    {
        u32x4 wds;
        wds[0] = cvt_pk_bf16(fast_tanh(e0[0]+d0[0]), fast_tanh(e0[1]+d0[1]));
        wds[1] = cvt_pk_bf16(fast_tanh(e0[2]+d0[2]), fast_tanh(e0[3]+d0[3]));
        wds[2] = cvt_pk_bf16(fast_tanh(e1[0]+d1[0]), fast_tanh(e1[1]+d1[1]));
        wds[3] = cvt_pk_bf16(fast_tanh(e1[2]+d1[2]), fast_tanh(e1[3]+d1[3]));
        *(u32x4*)(&lA0[srow * LDA + sk]) = wds;
    }
    e0 = *(const f32x4*)(ep + BK);     e1 = *(const f32x4*)(ep + BK + 4);
    d0 = *(const f32x4*)(dp + BK);     d1 = *(const f32x4*)(dp + BK + 4);
    RAW_BAR();

    f32x4 acc[4][4];
    #pragma unroll
    for (int m = 0; m < 4; ++m)
        #pragma unroll
        for (int f = 0; f < 4; ++f)
            acc[m][f] = (f32x4){0.f, 0.f, 0.f, 0.f};

    // ---- K-loop: 8 x 2 bodies; B reg-dbuf b0/b1, A LDS-dbuf lA0/lA1 ----
    #pragma unroll
    for (int kk = 0; kk < KSTEPS; kk += 2) {
        KBODY(kk,     lA0, lA1, b0, b1)
        KBODY(kk + 1, lA1, lA0, b1, b0)
    }

    // ---- epilogue: acc -> LDS 16-row chunks -> streaming f32x4 stores ----
    // raw barriers: stores ride in flight across chunks (and past endpgm)
    float bv[4];
    #pragma unroll
    for (int f = 0; f < 4; ++f) {
        int v = vb * BNB + wn * 64 + f * 16 + lr;
        bv[f] = (v < VV) ? bias[v] : 0.0f;
    }

    float* lchunk = (float*)smem;                 // 16 x LCH f32
    const int slabcols = (vb == 0) ? BNB : (VV - BNB);   // 256 or 244
    const int segmax   = slabcols >> 2;                   // 64 or 61
    float* outbase = out + (long)mb * BM * VV + vb * BNB;

    for (int c = 0; c < 4; ++c) {
        RAW_BAR();   // LDS free (K-loop done / previous chunk's reads done)
        #pragma unroll
        for (int f = 0; f < 4; ++f) {
            int vloc = wn * 64 + f * 16 + lr;
            #pragma unroll
            for (int q = 0; q < 4; ++q)
                lchunk[(lk * 4 + q) * LCH + vloc] = acc[c][f][q] + bv[f];
        }
        RAW_BAR();   // chunk writes visible
        // stream 16 rows x slabcols f32; per row a contiguous 1024/976 B run
        float* dst = outbase + c * 16 * VV;
        #pragma unroll
        for (int i = 0; i < 4; ++i) {
            int idx = i * THREADS + tid;        // 0..1023
            int row = idx >> 6;
            int seg = idx & 63;
            if (seg < segmax)
                *(f32x4*)(dst + row * VV + seg * 4) =
                    *(const f32x4*)(lchunk + row * LCH + seg * 4);
        }
    }
}

extern "C" void kernel_launch(void* const* d_in, const int* in_sizes, int n_in,
                              void* d_out, int out_size, void* d_ws, size_t ws_size,
                              hipStream_t stream) {
    const float* enc = (const float*)d_in[0];
    const float* dec = (const float*)d_in[1];
    const float* W   = (const float*)d_in[2];
    const float* b   = (const float*)d_in[3];
    float* out = (float*)d_out;
    unsigned short* Wt = (unsigned short*)d_ws;   // 512*512*2 = 512 KB

    prep_w<<<dim3((VP * DD) / 256), dim3(256), 0, stream>>>(W, Wt);
    joiner_kernel<<<dim3(MBLOCKS, 2), dim3(THREADS), 0, stream>>>(enc, dec, Wt, b, out);
}

// Round 16
// 130.692 us; speedup vs baseline: 1.1560x; 1.1560x over previous
//
#include <hip/hip_runtime.h>
#include <hip/hip_bf16.h>

// Joiner: logits[n,t,u,v] = sum_d tanh(enc[n,t,d]+dec[n,u,d]) * W[v,d] + b[v]
// N=8 T=200 U=100 D=512 V=500  -> GEMM M=160000, K=512, N=500 (padded 512)
//
// R13 = R10 (130.6us) with HALVED BARRIER COUNT: one barrier per 2 K-steps.
// A is a QUAD-buffer (4 x 5KB); interval s reads A[2s],A[2s+1], stages
// A[2s+2],A[2s+3] (any position in the interval is >=1 barrier after the
// conflicting read -- safe). B reg-dbuf rotates per K-step: b1 issued at
// interval top (consumed mid-interval), b0 re-issued mid (consumed next
// interval top) -- counted-vmcnt window ~600cyc, same 64 B-regs as R10.
// Barriers 15 -> 7. Raw (lgkm-only) barriers throughout (T4). Streamed
// LDS epilogue with raw barriers (ideal WRITE_SIZE).

#define NB 8
#define TT 200
#define UU 100
#define DD 512
#define VV 500
#define VP 512
#define BM 64
#define BK 32
#define KSTEPS 16          // 512/32
#define THREADS 256
#define LDA 40             // BK + 8 pad (ushort units, 80B row stride)
#define ABUF (BM*LDA)      // 2560 ushorts = 5120 B per A buffer
#define MROWS (NB*TT*UU)   // 160000
#define MBLOCKS (MROWS/BM) // 2500

typedef __attribute__((ext_vector_type(4))) float         f32x4;
typedef __attribute__((ext_vector_type(8))) short         s16x8;
typedef __attribute__((ext_vector_type(4))) unsigned int  u32x4;

#define RAW_BAR() do { asm volatile("s_waitcnt lgkmcnt(0)" ::: "memory"); \
                       __builtin_amdgcn_s_barrier(); } while (0)

__device__ __forceinline__ unsigned short f2bf(float f) {
    unsigned int u = __builtin_bit_cast(unsigned int, f);
    u = (u + 0x7FFFu + ((u >> 16) & 1u)) >> 16;   // round-to-nearest-even
    return (unsigned short)u;
}

// pack 2 f32 -> 2 bf16 (RNE) in one instruction
__device__ __forceinline__ unsigned int cvt_pk_bf16(float a, float b) {
    unsigned int r;
    asm("v_cvt_pk_bf16_f32 %0, %1, %2" : "=v"(r) : "v"(a), "v"(b));
    return r;
}

__device__ __forceinline__ float fast_tanh(float x) {
    // tanh(x) = 1 - 2/(1+2^(2x*log2e)); saturations via exp inf/0
    float e = __builtin_amdgcn_exp2f(x * 2.88539008177793f);
    return __builtin_fmaf(-2.0f, __builtin_amdgcn_rcpf(e + 1.0f), 1.0f);
}

// ---- prep: W (500x512 f32) -> bf16, padded to 512 rows, tiled [kc][v][32] ----
__global__ void prep_w(const float* __restrict__ W, unsigned short* __restrict__ Wt) {
    int idx = blockIdx.x * 256 + threadIdx.x;   // 0 .. 512*512-1
    int k = idx & 511;
    int v = idx >> 9;
    float val = (v < VV) ? W[v * DD + k] : 0.0f;
    Wt[(k >> 5) * (VP * BK) + v * BK + (k & 31)] = f2bf(val);
}

__global__ __launch_bounds__(THREADS, 2) void joiner_kernel(
    const float* __restrict__ enc, const float* __restrict__ dec,
    const unsigned short* __restrict__ Wt, const float* __restrict__ bias,
    float* __restrict__ out)
{
    // union: A quad-buffer (4 x 5120 = 20480 B) / epilogue chunk (32000 B)
    __shared__ __align__(16) char smem[32000];
    unsigned short* lAb = (unsigned short*)smem;

    const int tid  = threadIdx.x;
    const int mb   = blockIdx.x;
    const int lane = tid & 63;
    const int wn   = tid >> 6;       // 0..3: 128-col quarter
    const int lr   = lane & 15;
    const int lk   = lane >> 4;

    // staging: each thread produces 8 activations of one row per K-step
    const int srow = tid >> 2;          // 0..63
    const int sk   = (tid & 3) << 3;    // 0,8,16,24

    int r   = mb * BM + srow;
    int n   = r / (TT * UU);
    int rem = r - n * (TT * UU);
    int t   = rem / UU;
    int u   = rem - t * UU;
    const float* ep = enc + (n * TT + t) * DD + sk;
    const float* dp = dec + (n * UU + u) * DD + sk;

    // per-thread B pointer into pre-tiled Wt: v = wn*128 + f*16 + lr, k = lk*8
    const unsigned short* wptr = Wt + (wn * 128 + lr) * BK + lk * 8;

    s16x8 b0[8], b1[8];

    // ---- prologue: issue B[0]; stage A0, A1; raw barrier ----
    #pragma unroll
    for (int f = 0; f < 8; ++f)
        b0[f] = *(const s16x8*)(wptr + f * (16 * BK));
    {
        f32x4 eA0 = *(const f32x4*)(ep);          f32x4 eA1 = *(const f32x4*)(ep + 4);
        f32x4 dA0 = *(const f32x4*)(dp);          f32x4 dA1 = *(const f32x4*)(dp + 4);
        f32x4 eB0 = *(const f32x4*)(ep + BK);     f32x4 eB1 = *(const f32x4*)(ep + BK + 4);
        f32x4 dB0 = *(const f32x4*)(dp + BK);     f32x4 dB1 = *(const f32x4*)(dp + BK + 4);
        u32x4 w0, w1;
        w0[0] = cvt_pk_bf16(fast_tanh(eA0[0]+dA0[0]), fast_tanh(eA0[1]+dA0[1]));
        w0[1] = cvt_pk_bf16(fast_tanh(eA0[2]+dA0[2]), fast_tanh(eA0[3]+dA0[3]));
        w0[2] = cvt_pk_bf16(fast_tanh(eA1[0]+dA1[0]), fast_tanh(eA1[1]+dA1[1]));
        w0[3] = cvt_pk_bf16(fast_tanh(eA1[2]+dA1[2]), fast_tanh(eA1[3]+dA1[3]));
        *(u32x4*)(&lAb[0 * ABUF + srow * LDA + sk]) = w0;
        w1[0] = cvt_pk_bf16(fast_tanh(eB0[0]+dB0[0]), fast_tanh(eB0[1]+dB0[1]));
        w1[1] = cvt_pk_bf16(fast_tanh(eB0[2]+dB0[2]), fast_tanh(eB0[3]+dB0[3]));
        w1[2] = cvt_pk_bf16(fast_tanh(eB1[0]+dB1[0]), fast_tanh(eB1[1]+dB1[1]));
        w1[3] = cvt_pk_bf16(fast_tanh(eB1[2]+dB1[2]), fast_tanh(eB1[3]+dB1[3]));
        *(u32x4*)(&lAb[1 * ABUF + srow * LDA + sk]) = w1;
    }
    RAW_BAR();

    f32x4 acc[4][8];
    #pragma unroll
    for (int m = 0; m < 4; ++m)
        #pragma unroll
        for (int f = 0; f < 8; ++f)
            acc[m][f] = (f32x4){0.f, 0.f, 0.f, 0.f};

    // ---- K-loop: 8 super-steps, 1 barrier each ----
    #pragma unroll
    for (int s = 0; s < 8; ++s) {
        const int kc0 = 2 * s, kc1 = 2 * s + 1;
        unsigned short* bufR0 = lAb + (kc0 & 3) * ABUF;
        unsigned short* bufR1 = lAb + (kc1 & 3) * ABUF;
        unsigned short* bufW0 = lAb + ((kc0 + 2) & 3) * ABUF;
        unsigned short* bufW1 = lAb + ((kc1 + 2) & 3) * ABUF;

        // issue B[kc1] (consumed mid-interval)
        #pragma unroll
        for (int f = 0; f < 8; ++f)
            b1[f] = *(const s16x8*)(wptr + kc1 * (VP * BK) + f * (16 * BK));

        // early e/d loads for both stages (land under first MFMA cluster)
        f32x4 eA0, eA1, dA0, dA1, eB0, eB1, dB0, dB1;
        if (s < 7) {
            const float* eA = ep + (kc0 + 2) * BK;
            const float* dA = dp + (kc0 + 2) * BK;
            const float* eB = ep + (kc1 + 2) * BK;
            const float* dB = dp + (kc1 + 2) * BK;
            eA0 = *(const f32x4*)(eA);   eA1 = *(const f32x4*)(eA + 4);
            dA0 = *(const f32x4*)(dA);   dA1 = *(const f32x4*)(dA + 4);
            eB0 = *(const f32x4*)(eB);   eB1 = *(const f32x4*)(eB + 4);
            dB0 = *(const f32x4*)(dB);   dB1 = *(const f32x4*)(dB + 4);
        }

        // first half: aF(kc0), MFMA on b0
        {
            s16x8 aF[4];
            #pragma unroll
            for (int m = 0; m < 4; ++m)
                aF[m] = *(const s16x8*)(&bufR0[(m * 16 + lr) * LDA + lk * 8]);
            __builtin_amdgcn_s_setprio(1);
            #pragma unroll
            for (int m = 0; m < 4; ++m)
                #pragma unroll
                for (int f = 0; f < 8; ++f)
                    acc[m][f] = __builtin_amdgcn_mfma_f32_16x16x32_bf16(aF[m], b0[f], acc[m][f], 0, 0, 0);
            __builtin_amdgcn_s_setprio(0);
        }

        // re-issue b0 = B[kc0+2] (consumed at next interval top)
        if (s < 7) {
            #pragma unroll
            for (int f = 0; f < 8; ++f)
                b0[f] = *(const s16x8*)(wptr + (kc0 + 2) * (VP * BK) + f * (16 * BK));
        }

        // stages for next interval (>=1 barrier after conflicting reads)
        if (s < 7) {
            u32x4 w0, w1;
            w0[0] = cvt_pk_bf16(fast_tanh(eA0[0]+dA0[0]), fast_tanh(eA0[1]+dA0[1]));
            w0[1] = cvt_pk_bf16(fast_tanh(eA0[2]+dA0[2]), fast_tanh(eA0[3]+dA0[3]));
            w0[2] = cvt_pk_bf16(fast_tanh(eA1[0]+dA1[0]), fast_tanh(eA1[1]+dA1[1]));
            w0[3] = cvt_pk_bf16(fast_tanh(eA1[2]+dA1[2]), fast_tanh(eA1[3]+dA1[3]));
            *(u32x4*)(&bufW0[srow * LDA + sk]) = w0;
            w1[0] = cvt_pk_bf16(fast_tanh(eB0[0]+dB0[0]), fast_tanh(eB0[1]+dB0[1]));
            w1[1] = cvt_pk_bf16(fast_tanh(eB0[2]+dB0[2]), fast_tanh(eB0[3]+dB0[3]));
            w1[2] = cvt_pk_bf16(fast_tanh(eB1[0]+dB1[0]), fast_tanh(eB1[1]+dB1[1]));
            w1[3] = cvt_pk_bf16(fast_tanh(eB1[2]+dB1[2]), fast_tanh(eB1[3]+dB1[3]));
            *(u32x4*)(&bufW1[srow * LDA + sk]) = w1;
        }

        // second half: aF(kc1), MFMA on b1
        {
            s16x8 aF[4];
            #pragma unroll
            for (int m = 0; m < 4; ++m)
                aF[m] = *(const s16x8*)(&bufR1[(m * 16 + lr) * LDA + lk * 8]);
            __builtin_amdgcn_s_setprio(1);
            #pragma unroll
            for (int m = 0; m < 4; ++m)
                #pragma unroll
                for (int f = 0; f < 8; ++f)
                    acc[m][f] = __builtin_amdgcn_mfma_f32_16x16x32_bf16(aF[m], b1[f], acc[m][f], 0, 0, 0);
            __builtin_amdgcn_s_setprio(0);
        }

        if (s < 7) RAW_BAR();
    }

    // ---- epilogue: acc -> LDS 16-row chunks -> streaming f32x4 stores ----
    float bv[8];
    #pragma unroll
    for (int f = 0; f < 8; ++f) {
        int v = wn * 128 + f * 16 + lr;
        bv[f] = (v < VV) ? bias[v] : 0.0f;
    }

    float* lchunk = (float*)smem;                 // 16*500 f32 = 32000 B
    float* outbase = out + (long)mb * BM * VV;

    for (int m = 0; m < 4; ++m) {
        RAW_BAR();   // K-loop LDS reads done / previous chunk streamed
        #pragma unroll
        for (int f = 0; f < 8; ++f) {
            int v = wn * 128 + f * 16 + lr;
            if (v < VV) {
                #pragma unroll
                for (int q = 0; q < 4; ++q)
                    lchunk[(lk * 4 + q) * VV + v] = acc[m][f][q] + bv[f];
            }
        }
        RAW_BAR();   // chunk writes visible
        // 16 rows x 500 f32 = 8000 contiguous floats = 2000 f32x4
        float* dst = outbase + m * 16 * VV;
        #pragma unroll
        for (int i = 0; i < 8; ++i) {
            int c = i * THREADS + tid;
            if (c < 2000)
                *(f32x4*)(dst + c * 4) = *(const f32x4*)(lchunk + c * 4);
        }
    }
}

extern "C" void kernel_launch(void* const* d_in, const int* in_sizes, int n_in,
                              void* d_out, int out_size, void* d_ws, size_t ws_size,
                              hipStream_t stream) {
    const float* enc = (const float*)d_in[0];
    const float* dec = (const float*)d_in[1];
    const float* W   = (const float*)d_in[2];
    const float* b   = (const float*)d_in[3];
    float* out = (float*)d_out;
    unsigned short* Wt = (unsigned short*)d_ws;   // 512*512*2 = 512 KB

    prep_w<<<dim3((VP * DD) / 256), dim3(256), 0, stream>>>(W, Wt);
    joiner_kernel<<<dim3(MBLOCKS), dim3(THREADS), 0, stream>>>(enc, dec, Wt, b, out);
}